// Round 7
// baseline (308.175 us; speedup 1.0000x reference)
//
#include <hip/hip_runtime.h>

#define B_ 32
#define T_ 4096
#define C_ 256
#define R_ (B_*T_)
#define H1_ 128
#define H2_ 64

#define TB 32   // timestep rows per block in kernel 1

// output layout (floats), concatenated in reference return order
#define PROBS_OFF 0
#define TS_OFF  (R_*4)
#define SEG_OFF (TS_OFF + R_)
#define MI_OFF  (SEG_OFF + R_)
#define MC_OFF  (MI_OFF + R_)

// LDS float layout, 8320 floats = 33.3 KB -> 4 blocks/CU:
//   Phase A (conv):  XS [32][260] at 0
//   Phase B (GEMM1): W1S [32][128] linear at 0 (4096 f), H1S [32][130] at 4096 (4160 f)
//   Phase C (tail):  LG [32][17] at 0 (544 f)  (W1S dead)
#define XS_OFF  0
#define XS_P    260
#define W1S_OFF 0
#define H1S_OFF 4096
#define H1S_P   130
#define LG_OFF  0
#define LG_P    17
#define SMEMF   8320

typedef float f4s  __attribute__((ext_vector_type(4)));
typedef float f16s __attribute__((ext_vector_type(16)));

__global__ __launch_bounds__(256, 4) void mlp_conv_kernel(
    const float* __restrict__ X, const float* __restrict__ W1, const float* __restrict__ b1,
    const float* __restrict__ W2, const float* __restrict__ b2,
    const float* __restrict__ W3, const float* __restrict__ b3,
    const float* __restrict__ CW, const float* __restrict__ CB,
    float* __restrict__ out)
{
  __shared__ float sm[SMEMF];
  const int tid  = threadIdx.x;
  const int l    = tid & 63;
  const int w    = tid >> 6;
  const int row0 = blockIdx.x * TB;

  // ---- W1 chunk 0 prefetch (regs) — issued before XS staging barrier ----
  float4 st0 = *(const float4*)&W1[(tid +   0) * 4];
  float4 st1 = *(const float4*)&W1[(tid + 256) * 4];
  float4 st2 = *(const float4*)&W1[(tid + 512) * 4];
  float4 st3 = *(const float4*)&W1[(tid + 768) * 4];

  // ---- stage X tile (32 rows x 256) into padded LDS (for conv only) ----
  #pragma unroll
  for (int i2 = 0; i2 < 8; ++i2) {
    int g = tid + 256 * i2;          // f4 index: 32*64 = 2048 total
    int r = g >> 6, m = g & 63;
    float4 v = *(const float4*)&X[(size_t)(row0 + r) * C_ + m * 4];
    *(float4*)&sm[XS_OFF + r * XS_P + m * 4] = v;
  }
  __syncthreads();

  // ---- conv1d (C->1, k=3, SAME over T) + sigmoid -> transition_scores ----
  {
    const int rowi = w * 8 + (l & 7);
    const int p = l >> 3;                        // 0..7
    const int grow = row0 + rowi;
    const int tb = grow & (T_ - 1);              // t within its batch row
    float s = 0.f;
    #pragma unroll
    for (int cc = 0; cc < 8; ++cc) {
      const int c = p * 32 + cc * 4;
      float4 x0 = *(const float4*)&sm[XS_OFF + rowi * XS_P + c];
      float4 xm, xp;
      if (tb == 0)             xm = make_float4(0.f, 0.f, 0.f, 0.f);
      else if (rowi >= 1)      xm = *(const float4*)&sm[XS_OFF + (rowi - 1) * XS_P + c];
      else                     xm = *(const float4*)&X[(size_t)(grow - 1) * C_ + c];
      if (tb == T_ - 1)        xp = make_float4(0.f, 0.f, 0.f, 0.f);
      else if (rowi + 1 < TB)  xp = *(const float4*)&sm[XS_OFF + (rowi + 1) * XS_P + c];
      else                     xp = *(const float4*)&X[(size_t)(grow + 1) * C_ + c];
      float4 wa = *(const float4*)&CW[c * 3 + 0];
      float4 wb = *(const float4*)&CW[c * 3 + 4];
      float4 wc = *(const float4*)&CW[c * 3 + 8];
      s += xm.x * wa.x + x0.x * wa.y + xp.x * wa.z;
      s += xm.y * wa.w + x0.y * wb.x + xp.y * wb.y;
      s += xm.z * wb.z + x0.z * wb.w + xp.z * wc.x;
      s += xm.w * wc.y + x0.w * wc.z + xp.w * wc.w;
    }
    s += __shfl_xor(s, 8);
    s += __shfl_xor(s, 16);
    s += __shfl_xor(s, 32);
    if (p == 0) out[TS_OFF + grow] = 1.f / (1.f + expf(-(s + CB[0])));
  }
  __syncthreads();   // conv done reading XS; region freed for W1S/H1S

  // ---- GEMM1: (32x256)@(256x128). Wave w -> rows w*8..w*8+7, lane -> cols {2l,2l+1}.
  //      A: X rows via SGPR s_load (scalar pipe, early-clobber outputs).
  //      B: W1 LDS chunks, conflict-free ds_read_b64. ----
  const int wvu = __builtin_amdgcn_readfirstlane(w);
  const float* xw = X + (size_t)(row0 + wvu * 8) * C_;
  float2 acc[8];
  #pragma unroll
  for (int r = 0; r < 8; ++r) acc[r] = make_float2(0.f, 0.f);

  for (int kc = 0; kc < 8; ++kc) {
    // write staged W1 chunk (32 k-rows x 128) to LDS linear
    *(float4*)&sm[W1S_OFF + (tid +   0) * 4] = st0;
    *(float4*)&sm[W1S_OFF + (tid + 256) * 4] = st1;
    *(float4*)&sm[W1S_OFF + (tid + 512) * 4] = st2;
    *(float4*)&sm[W1S_OFF + (tid + 768) * 4] = st3;
    __syncthreads();
    if (kc + 1 < 8) {   // prefetch next W1 chunk; latency hidden under compute
      const float* wp = W1 + (size_t)(kc + 1) * 4096;
      st0 = *(const float4*)&wp[(tid +   0) * 4];
      st1 = *(const float4*)&wp[(tid + 256) * 4];
      st2 = *(const float4*)&wp[(tid + 512) * 4];
      st3 = *(const float4*)&wp[(tid + 768) * 4];
    }
    #pragma unroll
    for (int ka = 0; ka < 8; ++ka) {
      const float* xka = xw + kc * 32 + ka * 4;   // uniform (SGPR) pointer
      f4s a0, a1, a2, a3, a4, a5, a6, a7;
      asm volatile(
        "s_load_dwordx4 %0, %8, 0x0\n\t"
        "s_load_dwordx4 %1, %8, 0x400\n\t"
        "s_load_dwordx4 %2, %8, 0x800\n\t"
        "s_load_dwordx4 %3, %8, 0xc00\n\t"
        "s_load_dwordx4 %4, %8, 0x1000\n\t"
        "s_load_dwordx4 %5, %8, 0x1400\n\t"
        "s_load_dwordx4 %6, %8, 0x1800\n\t"
        "s_load_dwordx4 %7, %8, 0x1c00\n\t"
        "s_waitcnt lgkmcnt(0)"
        : "=&s"(a0), "=&s"(a1), "=&s"(a2), "=&s"(a3),
          "=&s"(a4), "=&s"(a5), "=&s"(a6), "=&s"(a7)
        : "s"(xka));
      #pragma unroll
      for (int kk = 0; kk < 4; ++kk) {
        const int krow = ka * 4 + kk;
        float2 bv = *(const float2*)&sm[W1S_OFF + krow * H1_ + 2 * l];
        #define G1R(r, av) { float as_ = (av)[kk]; \
          acc[r].x = fmaf(as_, bv.x, acc[r].x); \
          acc[r].y = fmaf(as_, bv.y, acc[r].y); }
        G1R(0, a0) G1R(1, a1) G1R(2, a2) G1R(3, a3)
        G1R(4, a4) G1R(5, a5) G1R(6, a6) G1R(7, a7)
        #undef G1R
      }
    }
    __syncthreads();   // all reads of this chunk done before next write
  }

  // ---- bias+relu -> H1S [32][130] ----
  {
    float2 b1v = *(const float2*)&b1[2 * l];
    #pragma unroll
    for (int r = 0; r < 8; ++r) {
      float2 h;
      h.x = fmaxf(acc[r].x + b1v.x, 0.f);
      h.y = fmaxf(acc[r].y + b1v.y, 0.f);
      *(float2*)&sm[H1S_OFF + (wvu * 8 + r) * H1S_P + 2 * l] = h;
    }
  }
  __syncthreads();

  // ---- GEMM2: (32x128)@(128x64). Lane -> row l&31 (2x dup), wave -> cols w*16..+15.
  //      A: ds_read_b64 from H1S. B: W2 via SGPR s_load, 2 k-rows per asm. ----
  const int rr = l & 31;
  const int abase = H1S_OFF + rr * H1S_P;
  const float* w2w = W2 + wvu * 16;
  float4 acc2[4];
  #pragma unroll
  for (int j = 0; j < 4; ++j) acc2[j] = make_float4(0.f, 0.f, 0.f, 0.f);
  for (int g = 0; g < 64; ++g) {                 // 2 k-rows per iter
    const float* w2k = w2w + (size_t)g * 128;    // row 2g, this wave's col base
    f16s B0, B1;
    asm volatile(
      "s_load_dwordx16 %0, %2, 0x0\n\t"
      "s_load_dwordx16 %1, %2, 0x100\n\t"
      "s_waitcnt lgkmcnt(0)"
      : "=&s"(B0), "=&s"(B1)
      : "s"(w2k));
    float2 av = *(const float2*)&sm[abase + 2 * g];
    #define G2K(av_, Bv) { float a_ = (av_); \
      acc2[0].x = fmaf(a_, (Bv)[0],  acc2[0].x); acc2[0].y = fmaf(a_, (Bv)[1],  acc2[0].y); \
      acc2[0].z = fmaf(a_, (Bv)[2],  acc2[0].z); acc2[0].w = fmaf(a_, (Bv)[3],  acc2[0].w); \
      acc2[1].x = fmaf(a_, (Bv)[4],  acc2[1].x); acc2[1].y = fmaf(a_, (Bv)[5],  acc2[1].y); \
      acc2[1].z = fmaf(a_, (Bv)[6],  acc2[1].z); acc2[1].w = fmaf(a_, (Bv)[7],  acc2[1].w); \
      acc2[2].x = fmaf(a_, (Bv)[8],  acc2[2].x); acc2[2].y = fmaf(a_, (Bv)[9],  acc2[2].y); \
      acc2[2].z = fmaf(a_, (Bv)[10], acc2[2].z); acc2[2].w = fmaf(a_, (Bv)[11], acc2[2].w); \
      acc2[3].x = fmaf(a_, (Bv)[12], acc2[3].x); acc2[3].y = fmaf(a_, (Bv)[13], acc2[3].y); \
      acc2[3].z = fmaf(a_, (Bv)[14], acc2[3].z); acc2[3].w = fmaf(a_, (Bv)[15], acc2[3].w); }
    G2K(av.x, B0)
    G2K(av.y, B1)
    #undef G2K
  }

  // ---- ReLU+b2 -> h2[16] registers; GEMM3 partials via SGPR W3 ----
  float h2[16];
  {
    const float* b2w = b2 + wvu * 16;
    #pragma unroll
    for (int j = 0; j < 4; ++j) {
      h2[j*4+0] = fmaxf(((const float*)&acc2[j])[0] + b2w[j*4+0], 0.f);
      h2[j*4+1] = fmaxf(((const float*)&acc2[j])[1] + b2w[j*4+1], 0.f);
      h2[j*4+2] = fmaxf(((const float*)&acc2[j])[2] + b2w[j*4+2], 0.f);
      h2[j*4+3] = fmaxf(((const float*)&acc2[j])[3] + b2w[j*4+3], 0.f);
    }
  }
  float4 L = make_float4(0.f, 0.f, 0.f, 0.f);
  {
    const float* w3w = W3 + wvu * 64;   // rows w*16..w*16+15, 64 contiguous floats
    f16s C0, C1, C2, C3;
    asm volatile(
      "s_load_dwordx16 %0, %2, 0x0\n\t"
      "s_load_dwordx16 %1, %2, 0x40\n\t"
      "s_waitcnt lgkmcnt(0)"
      : "=&s"(C0), "=&s"(C1) : "s"(w3w));
    asm volatile(
      "s_load_dwordx16 %0, %2, 0x80\n\t"
      "s_load_dwordx16 %1, %2, 0xc0\n\t"
      "s_waitcnt lgkmcnt(0)"
      : "=&s"(C2), "=&s"(C3) : "s"(w3w));
    #define G3C(c, Cv) { float hh = h2[c]; \
      L.x = fmaf(hh, (Cv)[((c)&3)*4+0], L.x); L.y = fmaf(hh, (Cv)[((c)&3)*4+1], L.y); \
      L.z = fmaf(hh, (Cv)[((c)&3)*4+2], L.z); L.w = fmaf(hh, (Cv)[((c)&3)*4+3], L.w); }
    G3C(0,C0)  G3C(1,C0)  G3C(2,C0)  G3C(3,C0)
    G3C(4,C1)  G3C(5,C1)  G3C(6,C1)  G3C(7,C1)
    G3C(8,C2)  G3C(9,C2)  G3C(10,C2) G3C(11,C2)
    G3C(12,C3) G3C(13,C3) G3C(14,C3) G3C(15,C3)
    #undef G3C
  }
  // ---- logit partial reduce across waves via LG [32][17] (W1S region dead) ----
  if (l < 32) {
    sm[LG_OFF + rr * LG_P + wvu * 4 + 0] = L.x;
    sm[LG_OFF + rr * LG_P + wvu * 4 + 1] = L.y;
    sm[LG_OFF + rr * LG_P + wvu * 4 + 2] = L.z;
    sm[LG_OFF + rr * LG_P + wvu * 4 + 3] = L.w;
  }
  __syncthreads();

  // ---- sum partials + softmax + dom/conf ----
  if (tid < 128) {
    const int row = tid >> 2, j = tid & 3;
    float lsum = (sm[LG_OFF + row * LG_P + 0 + j] + sm[LG_OFF + row * LG_P + 4 + j])
               + (sm[LG_OFF + row * LG_P + 8 + j] + sm[LG_OFF + row * LG_P + 12 + j]);
    float lv = lsum + b3[j];
    float n1v = __shfl_xor(lv, 1);
    float n2v = __shfl_xor(lv, 2);
    float n3v = __shfl_xor(lv, 3);
    float L0 = (j == 0) ? lv : (j == 1) ? n1v : (j == 2) ? n2v : n3v;
    float L1 = (j == 1) ? lv : (j == 0) ? n1v : (j == 2) ? n3v : n2v;
    float L2 = (j == 2) ? lv : (j == 0) ? n2v : (j == 1) ? n3v : n1v;
    float L3 = (j == 3) ? lv : (j == 0) ? n3v : (j == 1) ? n2v : n1v;
    float mx = fmaxf(fmaxf(L0, L1), fmaxf(L2, L3));
    float e0 = expf(L0 - mx), e1 = expf(L1 - mx), e2 = expf(L2 - mx), e3 = expf(L3 - mx);
    float inv = 1.f / ((e0 + e1) + (e2 + e3));
    float p0 = e0 * inv, p1 = e1 * inv, p2 = e2 * inv, p3 = e3 * inv;
    const int grow = row0 + row;
    float pown = (j == 0) ? p0 : (j == 1) ? p1 : (j == 2) ? p2 : p3;
    out[PROBS_OFF + (size_t)grow * 4 + j] = pown;
    if (j == 0) {
      int dom = 0; float pm = p0;
      if (p1 > pm) { pm = p1; dom = 1; }
      if (p2 > pm) { pm = p2; dom = 2; }
      if (p3 > pm) { pm = p3; dom = 3; }
      out[MI_OFF + grow] = (float)dom;   // park dom for kernel 2
      out[MC_OFF + grow] = pm;           // park conf for kernel 2
    }
  }
}

// ---- kernel 2: per-batch-row segmentation + segment means ----
__global__ __launch_bounds__(1024, 1) void seg_kernel(
    const float* __restrict__ inten, float* __restrict__ out)
{
  __shared__ float scnt[T_], ssi[T_], ssc[T_];
  __shared__ int wtot[16], wexcl[16];
  const int tid = threadIdx.x;
  const int lane = tid & 63, wid = tid >> 6;
  const size_t base = (size_t)blockIdx.x * T_;
  const float* tsS = out + TS_OFF;
  float* segO = out + SEG_OFF;
  float* miO  = out + MI_OFF;
  float* mcO  = out + MC_OFF;
  const int t4 = tid * 4;

  float4 dv = *(const float4*)&miO[base + t4];        // dom (as float)
  float4 tv = *(const float4*)&tsS[base + t4];        // transition scores
  float4 iv = *(const float4*)&inten[base + t4];      // intensity
  float4 cv = *(const float4*)&mcO[base + t4];        // confidence
  float pd = (tid == 0) ? 0.f : miO[base + t4 - 1];

  for (int i = tid; i < T_; i += 1024) { scnt[i] = 0.f; ssi[i] = 0.f; ssc[i] = 0.f; }

  int c0 = (t4 == 0) ? 0 : (((dv.x != pd)   || (tv.x > 0.7f)) ? 1 : 0);
  int c1 = ((dv.y != dv.x) || (tv.y > 0.7f)) ? 1 : 0;
  int c2 = ((dv.z != dv.y) || (tv.z > 0.7f)) ? 1 : 0;
  int c3 = ((dv.w != dv.z) || (tv.w > 0.7f)) ? 1 : 0;
  int l0 = c0, l1 = c0 + c1, l2 = l1 + c2, l3 = l2 + c3;
  const int tsum = l3;

  // wave-inclusive scan of per-thread sums
  int v = tsum;
  #pragma unroll
  for (int d = 1; d < 64; d <<= 1) {
    int o = __shfl_up(v, (unsigned)d);
    if (lane >= d) v += o;
  }
  if (lane == 63) wtot[wid] = v;
  __syncthreads();
  if (tid < 16) {
    int x = wtot[tid];
    int xx = x;
    #pragma unroll
    for (int d = 1; d < 16; d <<= 1) {
      int o = __shfl_up(xx, (unsigned)d);
      if (tid >= d) xx += o;
    }
    wexcl[tid] = xx - x;   // exclusive wave offset
  }
  __syncthreads();
  const int texcl = wexcl[wid] + (v - tsum);
  const int s0 = texcl + l0, s1 = texcl + l1, s2 = texcl + l2, s3 = texcl + l3;

  // merged LDS atomics for segment sums
  {
    int cur = s0; float aI = iv.x, aC = cv.x, aN = 1.f;
    if (s1 == cur) { aI += iv.y; aC += cv.y; aN += 1.f; }
    else { atomicAdd(&ssi[cur], aI); atomicAdd(&ssc[cur], aC); atomicAdd(&scnt[cur], aN);
           cur = s1; aI = iv.y; aC = cv.y; aN = 1.f; }
    if (s2 == cur) { aI += iv.z; aC += cv.z; aN += 1.f; }
    else { atomicAdd(&ssi[cur], aI); atomicAdd(&ssc[cur], aC); atomicAdd(&scnt[cur], aN);
           cur = s2; aI = iv.z; aC = cv.z; aN = 1.f; }
    if (s3 == cur) { aI += iv.w; aC += cv.w; aN += 1.f; }
    else { atomicAdd(&ssi[cur], aI); atomicAdd(&ssc[cur], aC); atomicAdd(&scnt[cur], aN);
           cur = s3; aI = iv.w; aC = cv.w; aN = 1.f; }
    atomicAdd(&ssi[cur], aI); atomicAdd(&ssc[cur], aC); atomicAdd(&scnt[cur], aN);
  }
  __syncthreads();

  float n0 = scnt[s0], n1 = scnt[s1], n2 = scnt[s2], n3 = scnt[s3];
  float4 m4, q4, g4;
  m4.x = ssi[s0] / n0; m4.y = ssi[s1] / n1; m4.z = ssi[s2] / n2; m4.w = ssi[s3] / n3;
  q4.x = ssc[s0] / n0; q4.y = ssc[s1] / n1; q4.z = ssc[s2] / n2; q4.w = ssc[s3] / n3;
  g4.x = (float)s0; g4.y = (float)s1; g4.z = (float)s2; g4.w = (float)s3;
  *(float4*)&segO[base + t4] = g4;
  *(float4*)&miO[base + t4]  = m4;
  *(float4*)&mcO[base + t4]  = q4;
}

extern "C" void kernel_launch(void* const* d_in, const int* in_sizes, int n_in,
                              void* d_out, int out_size, void* d_ws, size_t ws_size,
                              hipStream_t stream) {
  (void)in_sizes; (void)n_in; (void)out_size; (void)d_ws; (void)ws_size;
  const float* X   = (const float*)d_in[0];
  const float* INT = (const float*)d_in[1];
  const float* W1  = (const float*)d_in[2];
  const float* B1  = (const float*)d_in[3];
  const float* W2  = (const float*)d_in[4];
  const float* B2  = (const float*)d_in[5];
  const float* W3  = (const float*)d_in[6];
  const float* B3  = (const float*)d_in[7];
  const float* CW  = (const float*)d_in[8];
  const float* CB  = (const float*)d_in[9];
  float* out = (float*)d_out;

  hipLaunchKernelGGL(mlp_conv_kernel, dim3(R_ / TB), dim3(256), 0, stream,
                     X, W1, B1, W2, B2, W3, B3, CW, CB, out);
  hipLaunchKernelGGL(seg_kernel, dim3(B_), dim3(1024), 0, stream, INT, out);
}

// Round 8
// 179.479 us; speedup vs baseline: 1.7171x; 1.7171x over previous
//
#include <hip/hip_runtime.h>

#define B_ 32
#define T_ 4096
#define C_ 256
#define R_ (B_*T_)
#define H1_ 128
#define H2_ 64

#define TB 64   // timestep rows per block in kernel 1

// output layout (floats), concatenated in reference return order
#define PROBS_OFF 0
#define TS_OFF  (R_*4)
#define SEG_OFF (TS_OFF + R_)
#define MI_OFF  (SEG_OFF + R_)
#define MC_OFF  (MI_OFF + R_)

// LDS float layout, 19200 floats = 76.8 KB -> 2 blocks/CU:
//   Phase A (conv+GEMM1): XS [64][268] at 0 (17152 f), W1S [16][128] at 17152 (2048 f)
//   Phase B (GEMM2+):     H1S [64][132] at 0 (8448 f), W2S [128][64] at 8448 (8192 f)
#define XS_OFF  0
#define XS_P    268
#define H1S_OFF 0
#define H1S_P   132
#define W2S_OFF 8448
#define W1S_OFF 17152
#define SMEMF   19200

__device__ __forceinline__ void fma4(float4& a, float s, const float4& b) {
  a.x = fmaf(s, b.x, a.x); a.y = fmaf(s, b.y, a.y);
  a.z = fmaf(s, b.z, a.z); a.w = fmaf(s, b.w, a.w);
}

__global__ __launch_bounds__(256, 2) void mlp_conv_kernel(
    const float* __restrict__ X, const float* __restrict__ W1, const float* __restrict__ b1,
    const float* __restrict__ W2, const float* __restrict__ b2,
    const float* __restrict__ W3, const float* __restrict__ b3,
    const float* __restrict__ CW, const float* __restrict__ CB,
    float* __restrict__ out)
{
  __shared__ float sm[SMEMF];
  const int tid  = threadIdx.x;
  const int l    = tid & 63;
  const int w    = tid >> 6;
  const int row0 = blockIdx.x * TB;

  // ---- W1 chunk 0 (16 k-rows) prefetch into regs ----
  float4 st0 = ((const float4*)W1)[tid];
  float4 st1 = ((const float4*)W1)[tid + 256];

  // ---- stage X tile (64 rows x 256) into padded LDS ----
  #pragma unroll
  for (int i2 = 0; i2 < 16; ++i2) {
    int g = tid + 256 * i2;          // f4 index: 64*64 = 4096 total
    int r = g >> 6, m = g & 63;
    float4 v = *(const float4*)&X[(size_t)(row0 + r) * C_ + m * 4];
    *(float4*)&sm[XS_OFF + r * XS_P + m * 4] = v;
  }
  __syncthreads();

  // ---- conv1d (C->1, k=3, SAME over T) + sigmoid -> transition_scores ----
  // identical per-row arithmetic to the R5 kernel (bit-identical ts), run
  // twice: rows [0,32) then [32,64). p = l>>3 (8 partials x 32 ch).
  #pragma unroll
  for (int half = 0; half < 2; ++half) {
    const int rowi = half * 32 + w * 8 + (l & 7);
    const int p = l >> 3;                        // 0..7
    const int grow = row0 + rowi;
    const int tb = grow & (T_ - 1);              // t within its batch row
    float s = 0.f;
    #pragma unroll
    for (int cc = 0; cc < 8; ++cc) {
      const int c = p * 32 + cc * 4;
      float4 x0 = *(const float4*)&sm[XS_OFF + rowi * XS_P + c];
      float4 xm, xp;
      if (tb == 0)             xm = make_float4(0.f, 0.f, 0.f, 0.f);
      else if (rowi >= 1)      xm = *(const float4*)&sm[XS_OFF + (rowi - 1) * XS_P + c];
      else                     xm = *(const float4*)&X[(size_t)(grow - 1) * C_ + c];
      if (tb == T_ - 1)        xp = make_float4(0.f, 0.f, 0.f, 0.f);
      else if (rowi + 1 < TB)  xp = *(const float4*)&sm[XS_OFF + (rowi + 1) * XS_P + c];
      else                     xp = *(const float4*)&X[(size_t)(grow + 1) * C_ + c];
      float4 wa = *(const float4*)&CW[c * 3 + 0];
      float4 wb = *(const float4*)&CW[c * 3 + 4];
      float4 wc = *(const float4*)&CW[c * 3 + 8];
      s += xm.x * wa.x + x0.x * wa.y + xp.x * wa.z;
      s += xm.y * wa.w + x0.y * wb.x + xp.y * wb.y;
      s += xm.z * wb.z + x0.z * wb.w + xp.z * wc.x;
      s += xm.w * wc.y + x0.w * wc.z + xp.w * wc.w;
    }
    s += __shfl_xor(s, 8);
    s += __shfl_xor(s, 16);
    s += __shfl_xor(s, 32);
    if (p == 0) out[TS_OFF + grow] = 1.f / (1.f + expf(-(s + CB[0])));
  }

  // ---- GEMM1: (64x256)@(256x128), 8x4 per thread.
  //      A: X tile in LDS (broadcast b128). B: W1 in 16-row chunks,
  //      global->reg->LDS with 1-chunk-ahead prefetch. k-order sequential. ----
  const int rt = tid >> 5, ct = tid & 31;   // 8 row-groups x 32 col-groups
  const int rb = rt * 8;
  float4 acc[8];
  #pragma unroll
  for (int r = 0; r < 8; ++r) acc[r] = make_float4(0.f, 0.f, 0.f, 0.f);

  for (int kc = 0; kc < 16; ++kc) {
    *(float4*)&sm[W1S_OFF + tid * 4]         = st0;
    *(float4*)&sm[W1S_OFF + (tid + 256) * 4] = st1;
    __syncthreads();
    if (kc + 1 < 16) {   // prefetch next W1 chunk (latency hidden under compute)
      const float* wp = W1 + (size_t)(kc + 1) * 2048;
      st0 = ((const float4*)wp)[tid];
      st1 = ((const float4*)wp)[tid + 256];
    } else {             // prefetch W2 first quarter
      st0 = ((const float4*)W2)[tid];
      st1 = ((const float4*)W2)[tid + 256];
    }
    #pragma unroll
    for (int k4 = 0; k4 < 4; ++k4) {
      const int kb = kc * 16 + k4 * 4;
      float4 a0 = *(const float4*)&sm[XS_OFF + (rb + 0) * XS_P + kb];
      float4 a1 = *(const float4*)&sm[XS_OFF + (rb + 1) * XS_P + kb];
      float4 a2 = *(const float4*)&sm[XS_OFF + (rb + 2) * XS_P + kb];
      float4 a3 = *(const float4*)&sm[XS_OFF + (rb + 3) * XS_P + kb];
      float4 a4 = *(const float4*)&sm[XS_OFF + (rb + 4) * XS_P + kb];
      float4 a5 = *(const float4*)&sm[XS_OFF + (rb + 5) * XS_P + kb];
      float4 a6 = *(const float4*)&sm[XS_OFF + (rb + 6) * XS_P + kb];
      float4 a7 = *(const float4*)&sm[XS_OFF + (rb + 7) * XS_P + kb];
      float4 q0 = *(const float4*)&sm[W1S_OFF + (k4 * 4 + 0) * H1_ + ct * 4];
      float4 q1 = *(const float4*)&sm[W1S_OFF + (k4 * 4 + 1) * H1_ + ct * 4];
      float4 q2 = *(const float4*)&sm[W1S_OFF + (k4 * 4 + 2) * H1_ + ct * 4];
      float4 q3 = *(const float4*)&sm[W1S_OFF + (k4 * 4 + 3) * H1_ + ct * 4];
      fma4(acc[0], a0.x, q0); fma4(acc[0], a0.y, q1); fma4(acc[0], a0.z, q2); fma4(acc[0], a0.w, q3);
      fma4(acc[1], a1.x, q0); fma4(acc[1], a1.y, q1); fma4(acc[1], a1.z, q2); fma4(acc[1], a1.w, q3);
      fma4(acc[2], a2.x, q0); fma4(acc[2], a2.y, q1); fma4(acc[2], a2.z, q2); fma4(acc[2], a2.w, q3);
      fma4(acc[3], a3.x, q0); fma4(acc[3], a3.y, q1); fma4(acc[3], a3.z, q2); fma4(acc[3], a3.w, q3);
      fma4(acc[4], a4.x, q0); fma4(acc[4], a4.y, q1); fma4(acc[4], a4.z, q2); fma4(acc[4], a4.w, q3);
      fma4(acc[5], a5.x, q0); fma4(acc[5], a5.y, q1); fma4(acc[5], a5.z, q2); fma4(acc[5], a5.w, q3);
      fma4(acc[6], a6.x, q0); fma4(acc[6], a6.y, q1); fma4(acc[6], a6.z, q2); fma4(acc[6], a6.w, q3);
      fma4(acc[7], a7.x, q0); fma4(acc[7], a7.y, q1); fma4(acc[7], a7.z, q2); fma4(acc[7], a7.w, q3);
    }
    __syncthreads();   // all reads of this chunk done before next write
  }

  // ---- epilogue staging: remaining W2 + W3/b3 regs (hidden under H1 writes) ----
  const int rt2 = tid >> 4, ct2 = tid & 15;
  float4 w2r[6];
  #pragma unroll
  for (int i = 0; i < 6; ++i) w2r[i] = ((const float4*)W2)[tid + 512 + 256 * i];
  float4 w30 = ((const float4*)W3)[ct2 * 4 + 0];
  float4 w31 = ((const float4*)W3)[ct2 * 4 + 1];
  float4 w32 = ((const float4*)W3)[ct2 * 4 + 2];
  float4 w33 = ((const float4*)W3)[ct2 * 4 + 3];
  float4 b3v = *(const float4*)&b3[0];

  // ---- bias+relu -> H1S [64][132] (overlays XS; XS dead after last barrier) ----
  {
    float4 bb = ((const float4*)b1)[ct];
    #pragma unroll
    for (int r = 0; r < 8; ++r) {
      float4 h = acc[r];
      h.x = fmaxf(h.x + bb.x, 0.f); h.y = fmaxf(h.y + bb.y, 0.f);
      h.z = fmaxf(h.z + bb.z, 0.f); h.w = fmaxf(h.w + bb.w, 0.f);
      *(float4*)&sm[H1S_OFF + (rb + r) * H1S_P + ct * 4] = h;
    }
  }
  // W2 -> LDS linear [128][64]
  *(float4*)&sm[W2S_OFF + tid * 4]         = st0;
  *(float4*)&sm[W2S_OFF + (tid + 256) * 4] = st1;
  #pragma unroll
  for (int i = 0; i < 6; ++i)
    *(float4*)&sm[W2S_OFF + (tid + 512 + 256 * i) * 4] = w2r[i];
  __syncthreads();

  // ---- GEMM2: (64x128)@(128x64), 4x4 per thread, both operands LDS ----
  float4 acc2[4];
  #pragma unroll
  for (int j = 0; j < 4; ++j) acc2[j] = make_float4(0.f, 0.f, 0.f, 0.f);
  #pragma unroll 4
  for (int k4 = 0; k4 < 32; ++k4) {
    float4 a0 = *(const float4*)&sm[H1S_OFF + (rt2 * 4 + 0) * H1S_P + k4 * 4];
    float4 a1 = *(const float4*)&sm[H1S_OFF + (rt2 * 4 + 1) * H1S_P + k4 * 4];
    float4 a2 = *(const float4*)&sm[H1S_OFF + (rt2 * 4 + 2) * H1S_P + k4 * 4];
    float4 a3 = *(const float4*)&sm[H1S_OFF + (rt2 * 4 + 3) * H1S_P + k4 * 4];
    float4 q0 = *(const float4*)&sm[W2S_OFF + (k4 * 4 + 0) * H2_ + ct2 * 4];
    float4 q1 = *(const float4*)&sm[W2S_OFF + (k4 * 4 + 1) * H2_ + ct2 * 4];
    float4 q2 = *(const float4*)&sm[W2S_OFF + (k4 * 4 + 2) * H2_ + ct2 * 4];
    float4 q3 = *(const float4*)&sm[W2S_OFF + (k4 * 4 + 3) * H2_ + ct2 * 4];
    fma4(acc2[0], a0.x, q0); fma4(acc2[0], a0.y, q1); fma4(acc2[0], a0.z, q2); fma4(acc2[0], a0.w, q3);
    fma4(acc2[1], a1.x, q0); fma4(acc2[1], a1.y, q1); fma4(acc2[1], a1.z, q2); fma4(acc2[1], a1.w, q3);
    fma4(acc2[2], a2.x, q0); fma4(acc2[2], a2.y, q1); fma4(acc2[2], a2.z, q2); fma4(acc2[2], a2.w, q3);
    fma4(acc2[3], a3.x, q0); fma4(acc2[3], a3.y, q1); fma4(acc2[3], a3.z, q2); fma4(acc2[3], a3.w, q3);
  }

  // ---- ReLU+b2 (regs); GEMM3 partials; butterfly over 16 col-groups ----
  float4 L[4];
  {
    float4 bb = ((const float4*)b2)[ct2];
    #pragma unroll
    for (int r = 0; r < 4; ++r) {
      float4 h = acc2[r];
      h.x = fmaxf(h.x + bb.x, 0.f); h.y = fmaxf(h.y + bb.y, 0.f);
      h.z = fmaxf(h.z + bb.z, 0.f); h.w = fmaxf(h.w + bb.w, 0.f);
      float4 t = make_float4(0.f, 0.f, 0.f, 0.f);
      fma4(t, h.x, w30); fma4(t, h.y, w31); fma4(t, h.z, w32); fma4(t, h.w, w33);
      L[r] = t;
    }
  }
  #pragma unroll
  for (int d = 1; d < 16; d <<= 1) {
    #pragma unroll
    for (int r = 0; r < 4; ++r) {
      L[r].x += __shfl_xor(L[r].x, d);
      L[r].y += __shfl_xor(L[r].y, d);
      L[r].z += __shfl_xor(L[r].z, d);
      L[r].w += __shfl_xor(L[r].w, d);
    }
  }

  // ---- softmax + dom/conf: lane ct2 (0..3) handles row rt2*4 + ct2 ----
  if (ct2 < 4) {
    float4 Lv = L[ct2];
    const int grow = row0 + rt2 * 4 + ct2;
    Lv.x += b3v.x; Lv.y += b3v.y; Lv.z += b3v.z; Lv.w += b3v.w;
    float mx = fmaxf(fmaxf(Lv.x, Lv.y), fmaxf(Lv.z, Lv.w));
    float e0 = expf(Lv.x - mx), e1 = expf(Lv.y - mx), e2 = expf(Lv.z - mx), e3 = expf(Lv.w - mx);
    float inv = 1.f / ((e0 + e1) + (e2 + e3));
    float p0 = e0 * inv, p1 = e1 * inv, p2 = e2 * inv, p3 = e3 * inv;
    *(float4*)&out[PROBS_OFF + (size_t)grow * 4] = make_float4(p0, p1, p2, p3);
    int dom = 0; float pm = p0;
    if (p1 > pm) { pm = p1; dom = 1; }
    if (p2 > pm) { pm = p2; dom = 2; }
    if (p3 > pm) { pm = p3; dom = 3; }
    out[MI_OFF + grow] = (float)dom;   // park dom for kernel 2
    out[MC_OFF + grow] = pm;           // park conf for kernel 2
  }
}

// ---- kernel 2: per-batch-row segmentation + segment means ----
__global__ __launch_bounds__(1024, 1) void seg_kernel(
    const float* __restrict__ inten, float* __restrict__ out)
{
  __shared__ float scnt[T_], ssi[T_], ssc[T_];
  __shared__ int wtot[16], wexcl[16];
  const int tid = threadIdx.x;
  const int lane = tid & 63, wid = tid >> 6;
  const size_t base = (size_t)blockIdx.x * T_;
  const float* tsS = out + TS_OFF;
  float* segO = out + SEG_OFF;
  float* miO  = out + MI_OFF;
  float* mcO  = out + MC_OFF;
  const int t4 = tid * 4;

  float4 dv = *(const float4*)&miO[base + t4];        // dom (as float)
  float4 tv = *(const float4*)&tsS[base + t4];        // transition scores
  float4 iv = *(const float4*)&inten[base + t4];      // intensity
  float4 cv = *(const float4*)&mcO[base + t4];        // confidence
  float pd = (tid == 0) ? 0.f : miO[base + t4 - 1];

  for (int i = tid; i < T_; i += 1024) { scnt[i] = 0.f; ssi[i] = 0.f; ssc[i] = 0.f; }

  int c0 = (t4 == 0) ? 0 : (((dv.x != pd)   || (tv.x > 0.7f)) ? 1 : 0);
  int c1 = ((dv.y != dv.x) || (tv.y > 0.7f)) ? 1 : 0;
  int c2 = ((dv.z != dv.y) || (tv.z > 0.7f)) ? 1 : 0;
  int c3 = ((dv.w != dv.z) || (tv.w > 0.7f)) ? 1 : 0;
  int l0 = c0, l1 = c0 + c1, l2 = l1 + c2, l3 = l2 + c3;
  const int tsum = l3;

  // wave-inclusive scan of per-thread sums
  int v = tsum;
  #pragma unroll
  for (int d = 1; d < 64; d <<= 1) {
    int o = __shfl_up(v, (unsigned)d);
    if (lane >= d) v += o;
  }
  if (lane == 63) wtot[wid] = v;
  __syncthreads();
  if (tid < 16) {
    int x = wtot[tid];
    int xx = x;
    #pragma unroll
    for (int d = 1; d < 16; d <<= 1) {
      int o = __shfl_up(xx, (unsigned)d);
      if (tid >= d) xx += o;
    }
    wexcl[tid] = xx - x;   // exclusive wave offset
  }
  __syncthreads();
  const int texcl = wexcl[wid] + (v - tsum);
  const int s0 = texcl + l0, s1 = texcl + l1, s2 = texcl + l2, s3 = texcl + l3;

  // merged LDS atomics for segment sums
  {
    int cur = s0; float aI = iv.x, aC = cv.x, aN = 1.f;
    if (s1 == cur) { aI += iv.y; aC += cv.y; aN += 1.f; }
    else { atomicAdd(&ssi[cur], aI); atomicAdd(&ssc[cur], aC); atomicAdd(&scnt[cur], aN);
           cur = s1; aI = iv.y; aC = cv.y; aN = 1.f; }
    if (s2 == cur) { aI += iv.z; aC += cv.z; aN += 1.f; }
    else { atomicAdd(&ssi[cur], aI); atomicAdd(&ssc[cur], aC); atomicAdd(&scnt[cur], aN);
           cur = s2; aI = iv.z; aC = cv.z; aN = 1.f; }
    if (s3 == cur) { aI += iv.w; aC += cv.w; aN += 1.f; }
    else { atomicAdd(&ssi[cur], aI); atomicAdd(&ssc[cur], aC); atomicAdd(&scnt[cur], aN);
           cur = s3; aI = iv.w; aC = cv.w; aN = 1.f; }
    atomicAdd(&ssi[cur], aI); atomicAdd(&ssc[cur], aC); atomicAdd(&scnt[cur], aN);
  }
  __syncthreads();

  float n0 = scnt[s0], n1 = scnt[s1], n2 = scnt[s2], n3 = scnt[s3];
  float4 m4, q4, g4;
  m4.x = ssi[s0] / n0; m4.y = ssi[s1] / n1; m4.z = ssi[s2] / n2; m4.w = ssi[s3] / n3;
  q4.x = ssc[s0] / n0; q4.y = ssc[s1] / n1; q4.z = ssc[s2] / n2; q4.w = ssc[s3] / n3;
  g4.x = (float)s0; g4.y = (float)s1; g4.z = (float)s2; g4.w = (float)s3;
  *(float4*)&segO[base + t4] = g4;
  *(float4*)&miO[base + t4]  = m4;
  *(float4*)&mcO[base + t4]  = q4;
}

extern "C" void kernel_launch(void* const* d_in, const int* in_sizes, int n_in,
                              void* d_out, int out_size, void* d_ws, size_t ws_size,
                              hipStream_t stream) {
  (void)in_sizes; (void)n_in; (void)out_size; (void)d_ws; (void)ws_size;
  const float* X   = (const float*)d_in[0];
  const float* INT = (const float*)d_in[1];
  const float* W1  = (const float*)d_in[2];
  const float* B1  = (const float*)d_in[3];
  const float* W2  = (const float*)d_in[4];
  const float* B2  = (const float*)d_in[5];
  const float* W3  = (const float*)d_in[6];
  const float* B3  = (const float*)d_in[7];
  const float* CW  = (const float*)d_in[8];
  const float* CB  = (const float*)d_in[9];
  float* out = (float*)d_out;

  hipLaunchKernelGGL(mlp_conv_kernel, dim3(R_ / TB), dim3(256), 0, stream,
                     X, W1, B1, W2, B2, W3, B3, CW, CB, out);
  hipLaunchKernelGGL(seg_kernel, dim3(B_), dim3(1024), 0, stream, INT, out);
}